// Round 2
// baseline (1893.680 us; speedup 1.0000x reference)
//
#include <hip/hip_runtime.h>

#define DIM    256
#define KMSG   768
#define KUPD   512
#define NNODES 50000
#define NEDGES 800000
#define EPSV   1e-6f

// ws layout (bytes) — UNCHANGED from the verified kernel:
//   agg   f32 [50000][256]  @ 0          (51,200,000)
//   cnt   i32 [50000]       @ 51,200,000 (200,000; region padded to 51,404,800)
//   Wt_msg bf16 [256][768]  @ 51,404,800 (393,216)
//   Wt_upd bf16 [256][512]  @ 51,798,016 (262,144)
//   flag  int               @ 52,060,160 (4)       -> total 52,060,164
// Sort scratch (perm 3.2MB + off 200KB) lives in d_out (>= 25.6MB even for
// bf16 output; fully overwritten by node_k afterwards in both dtype paths).
#define AGG_OFF   0
#define CNT_OFF   51200000
#define WTM_OFF   51404800
#define WTU_OFF   51798016
#define FLAG_OFF  52060160
#define WS_REQUIRED 52060164
#define ZERO_BYTES 51404800
#define PERM_OUT_OFF 0
#define OFF_OUT_OFF  3200000

typedef __attribute__((ext_vector_type(8))) short bf16x8;
typedef __attribute__((ext_vector_type(4))) float f32x4;

static __device__ __forceinline__ float bf2f(unsigned short h) {
    union { unsigned int u; float f; } v; v.u = ((unsigned int)h) << 16; return v.f;
}
static __device__ __forceinline__ unsigned short f2bf(float f) {
    union { float f; unsigned int u; } v; v.f = f;
    unsigned int r = v.u + 0x7fffu + ((v.u >> 16) & 1u);  // RNE (finite values)
    return (unsigned short)(r >> 16);
}

// ---- dtype detector: 0 = bf16 inputs, 1 = f32 inputs ----
__global__ void detect_k(const unsigned short* __restrict__ nf, int* __restrict__ flag) {
    if (blockIdx.x == 0 && threadIdx.x == 0) {
        int ok = 0;
        for (int i = 0; i < 512; i += 2) {
            unsigned int u = nf[i];
            unsigned int e = (u >> 7) & 0xFFu;
            if ((e >= 90u && e <= 150u) || (u & 0x7FFFu) == 0u) ++ok;
        }
        *flag = (ok >= 160) ? 0 : 1;
    }
}

// ---- one-time transpose of W_msg/W_upd into bf16 [n][k] layout ----
__global__ void transpose_k(const unsigned short* __restrict__ Wm16, const float* __restrict__ Wm32,
                            const unsigned short* __restrict__ Wu16, const float* __restrict__ Wu32,
                            unsigned short* __restrict__ Wtm, unsigned short* __restrict__ Wtu,
                            const int* __restrict__ flag) {
    const int fl = *flag;
    int i = blockIdx.x * 256 + threadIdx.x;
    if (i < KMSG * DIM) {
        int k = i >> 8, n = i & 255;
        Wtm[n * KMSG + k] = fl ? f2bf(Wm32[i]) : Wm16[i];
    }
    if (i < KUPD * DIM) {
        int k = i >> 8, n = i & 255;
        Wtu[n * KUPD + k] = fl ? f2bf(Wu32[i]) : Wu16[i];
    }
}

// ---- per-node in-degree counts (int) ----
__global__ void count_k(const int* __restrict__ col, int* __restrict__ cnt) {
    int e = blockIdx.x * 256 + threadIdx.x;
    if (e < NEDGES) atomicAdd(&cnt[col[e]], 1);
}

// ---- exclusive prefix sum of cnt[NNODES] -> off[NNODES], single block ----
__global__ __launch_bounds__(1024) void scan_k(const int* __restrict__ cnt, int* __restrict__ off) {
    __shared__ int part[1024];
    const int t = threadIdx.x;
    const int PER = (NNODES + 1023) / 1024;   // 49
    const int base = t * PER;
    int s = 0;
    for (int i = 0; i < PER; ++i) {
        int idx = base + i;
        if (idx < NNODES) s += cnt[idx];
    }
    part[t] = s;
    __syncthreads();
    for (int d = 1; d < 1024; d <<= 1) {       // inclusive Hillis-Steele
        int v = (t >= d) ? part[t - d] : 0;
        __syncthreads();
        part[t] += v;
        __syncthreads();
    }
    int run = part[t] - s;                     // exclusive base for this thread
    for (int i = 0; i < PER; ++i) {
        int idx = base + i;
        if (idx < NNODES) {
            off[idx] = run;
            run += cnt[idx];
        }
    }
}

// ---- counting-sort scatter: perm[] = edge ids sorted by destination ----
__global__ void scatter_k(const int* __restrict__ col, int* __restrict__ off,
                          int* __restrict__ perm) {
    int e = blockIdx.x * 256 + threadIdx.x;
    if (e < NEDGES) {
        int p = atomicAdd(&off[col[e]], 1);
        perm[p] = e;
    }
}

// ---- edge GEMM over destination-sorted edges + in-LDS segmented reduction ----
__global__ __launch_bounds__(256) void edge_k(
        const unsigned short* __restrict__ nf16, const float* __restrict__ nf32,
        const unsigned short* __restrict__ ef16, const float* __restrict__ ef32,
        const int* __restrict__ row, const int* __restrict__ col,
        const int* __restrict__ perm,
        const unsigned short* __restrict__ Wt,
        const unsigned short* __restrict__ bm16, const float* __restrict__ bm32,
        float* __restrict__ agg, const int* __restrict__ flag) {
    // Union: main loop uses sA bf16 [64][72] (9216 B); epilogue reuses the
    // buffer as f32 msg tile [4 waves][64 rows][34] (34816 B, 2-way banks).
    __shared__ __align__(16) char smem_raw[34816];
    __shared__ int snode[64];
    unsigned short (*sA)[72] = reinterpret_cast<unsigned short (*)[72]>(smem_raw);

    const int fl   = *flag;
    const int tid  = threadIdx.x;
    const int lane = tid & 63;
    const int wave = tid >> 6;
    const int e0   = blockIdx.x * 64;

    f32x4 acc[4][4];
#pragma unroll
    for (int i = 0; i < 4; ++i)
#pragma unroll
        for (int j = 0; j < 4; ++j) acc[i][j] = (f32x4){0.f, 0.f, 0.f, 0.f};

    const int e_loc = tid >> 2;      // 0..63 (sorted position within block)
    const int chunk = tid & 3;       // 16 elems each
    const int edge  = perm[e0 + e_loc];
    const int r = row[edge];
    const int c = col[edge];
    if (chunk == 0) snode[e_loc] = c;   // visible after first __syncthreads
    const unsigned short* ps16 = nf16 + (size_t)r * DIM;
    const unsigned short* pd16 = nf16 + (size_t)c * DIM;
    const unsigned short* pe16 = ef16 + (size_t)edge * DIM;
    const float* ps32 = nf32 + (size_t)r * DIM;
    const float* pd32 = nf32 + (size_t)c * DIM;
    const float* pe32 = ef32 + (size_t)edge * DIM;

    const int arow = lane & 15;
    const int quad = lane >> 4;

    for (int kt = 0; kt < 12; ++kt) {
        const int seg = kt >> 2;     // 0:src 1:dst 2:edge
        __align__(16) unsigned short tmp[16];
        if (fl) {
            const float* p = (seg == 0 ? ps32 : (seg == 1 ? pd32 : pe32)) + (kt & 3) * 64 + chunk * 16;
#pragma unroll
            for (int j = 0; j < 4; ++j) {
                float4 q = *(const float4*)(p + 4 * j);
                tmp[4 * j + 0] = f2bf(q.x); tmp[4 * j + 1] = f2bf(q.y);
                tmp[4 * j + 2] = f2bf(q.z); tmp[4 * j + 3] = f2bf(q.w);
            }
        } else {
            const unsigned short* p = (seg == 0 ? ps16 : (seg == 1 ? pd16 : pe16)) + (kt & 3) * 64 + chunk * 16;
            *(uint4*)&tmp[0] = *(const uint4*)p;
            *(uint4*)&tmp[8] = *(const uint4*)(p + 8);
        }
        __syncthreads();
        *(uint4*)&sA[e_loc][chunk * 16]     = *(uint4*)&tmp[0];
        *(uint4*)&sA[e_loc][chunk * 16 + 8] = *(uint4*)&tmp[8];
        __syncthreads();
        const int kbase = kt * 64;
#pragma unroll
        for (int kk = 0; kk < 64; kk += 32) {
            bf16x8 af[4], bfr[4];
#pragma unroll
            for (int mt = 0; mt < 4; ++mt)
                af[mt] = *(const bf16x8*)&sA[mt * 16 + arow][kk + quad * 8];
#pragma unroll
            for (int nt = 0; nt < 4; ++nt) {
                const int n = wave * 64 + nt * 16 + arow;
                bfr[nt] = *(const bf16x8*)&Wt[(size_t)n * KMSG + kbase + kk + quad * 8];
            }
#pragma unroll
            for (int mt = 0; mt < 4; ++mt)
#pragma unroll
                for (int nt = 0; nt < 4; ++nt)
                    acc[mt][nt] = __builtin_amdgcn_mfma_f32_16x16x32_bf16(
                        af[mt], bfr[nt], acc[mt][nt], 0, 0, 0);
        }
    }

    float bias[4];
#pragma unroll
    for (int nt = 0; nt < 4; ++nt) {
        const int ix = wave * 64 + nt * 16 + arow;
        bias[nt] = fl ? bm32[ix] : bf2f(bm16[ix]);
    }

    // ---- epilogue: bias+relu, in-LDS segmented reduction over sorted dsts ----
    __syncthreads();                           // all sA reads done; reuse smem
    float* smsg = reinterpret_cast<float*>(smem_raw);

#pragma unroll
    for (int p = 0; p < 2; ++p) {
        // write half the columns: wave's nt in {2p, 2p+1} -> local col 0..31
#pragma unroll
        for (int mt = 0; mt < 4; ++mt)
#pragma unroll
            for (int reg = 0; reg < 4; ++reg) {
                const int m = mt * 16 + quad * 4 + reg;   // C/D: row = quad*4+reg
#pragma unroll
                for (int nt2 = 0; nt2 < 2; ++nt2) {
                    const int nt = p * 2 + nt2;
                    float v = acc[mt][nt][reg] + bias[nt];
                    v = fmaxf(v, 0.f);
                    smsg[(wave * 64 + m) * 34 + nt2 * 16 + arow] = v;
                }
            }
        __syncthreads();
        // reduce: thread t owns column cidx = t>>1, rows (t&1)*32 .. +31
        {
            const int cidx = tid >> 1;         // 0..127
            const int half = tid & 1;
            const int w2   = cidx >> 5;        // source wave region
            const int cc   = cidx & 31;        // local col
            const int gcol = w2 * 64 + p * 32 + cc;
            float runv  = 0.f;
            int runnode = snode[half * 32];
            for (int rr = 0; rr < 32; ++rr) {
                const int rI = half * 32 + rr;
                const int nd = snode[rI];
                const float v = smsg[(w2 * 64 + rI) * 34 + cc];
                if (nd != runnode) {
                    atomicAdd(agg + (size_t)runnode * DIM + gcol, runv);
                    runv = 0.f; runnode = nd;
                }
                runv += v;
            }
            atomicAdd(agg + (size_t)runnode * DIM + gcol, runv);
        }
        __syncthreads();
    }
}

// ---- node GEMM: out = relu(concat(nf, agg/(cnt+eps)) @ Wupd + b) ----
__global__ __launch_bounds__(256) void node_k(
        const unsigned short* __restrict__ nf16, const float* __restrict__ nf32,
        const float* __restrict__ agg, const int* __restrict__ cnt,
        const unsigned short* __restrict__ Wt,
        const unsigned short* __restrict__ bu16, const float* __restrict__ bu32,
        unsigned short* __restrict__ out16, float* __restrict__ out32,
        const int* __restrict__ flag) {
    __shared__ __align__(16) unsigned short sA[64][72];
    const int fl   = *flag;
    const int tid  = threadIdx.x;
    const int lane = tid & 63;
    const int wave = tid >> 6;
    const int n0   = blockIdx.x * 64;

    f32x4 acc[4][4];
#pragma unroll
    for (int i = 0; i < 4; ++i)
#pragma unroll
        for (int j = 0; j < 4; ++j) acc[i][j] = (f32x4){0.f, 0.f, 0.f, 0.f};

    const int n_loc = tid >> 2;
    const int chunk = tid & 3;
    int node = n0 + n_loc;
    if (node >= NNODES) node = NNODES - 1;           // clamp loads; stores guarded
    const float rc = 1.0f / ((float)cnt[node] + EPSV);
    const unsigned short* pn16 = nf16 + (size_t)node * DIM;
    const float*          pn32 = nf32 + (size_t)node * DIM;
    const float*          pa   = agg  + (size_t)node * DIM;

    const int arow = lane & 15;
    const int quad = lane >> 4;

    for (int kt = 0; kt < 8; ++kt) {
        __align__(16) unsigned short tmp[16];
        if (kt < 4) {
            if (fl) {
                const float* p = pn32 + kt * 64 + chunk * 16;
#pragma unroll
                for (int j = 0; j < 4; ++j) {
                    float4 q = *(const float4*)(p + 4 * j);
                    tmp[4 * j + 0] = f2bf(q.x); tmp[4 * j + 1] = f2bf(q.y);
                    tmp[4 * j + 2] = f2bf(q.z); tmp[4 * j + 3] = f2bf(q.w);
                }
            } else {
                const unsigned short* p = pn16 + kt * 64 + chunk * 16;
                *(uint4*)&tmp[0] = *(const uint4*)p;
                *(uint4*)&tmp[8] = *(const uint4*)(p + 8);
            }
        } else {
            const float* p = pa + (kt - 4) * 64 + chunk * 16;
#pragma unroll
            for (int j = 0; j < 16; ++j) tmp[j] = f2bf(p[j] * rc);
        }
        __syncthreads();
        *(uint4*)&sA[n_loc][chunk * 16]     = *(uint4*)&tmp[0];
        *(uint4*)&sA[n_loc][chunk * 16 + 8] = *(uint4*)&tmp[8];
        __syncthreads();
        const int kbase = kt * 64;
#pragma unroll
        for (int kk = 0; kk < 64; kk += 32) {
            bf16x8 af[4], bfr[4];
#pragma unroll
            for (int mt = 0; mt < 4; ++mt)
                af[mt] = *(const bf16x8*)&sA[mt * 16 + arow][kk + quad * 8];
#pragma unroll
            for (int nt = 0; nt < 4; ++nt) {
                const int n = wave * 64 + nt * 16 + arow;
                bfr[nt] = *(const bf16x8*)&Wt[(size_t)n * KUPD + kbase + kk + quad * 8];
            }
#pragma unroll
            for (int mt = 0; mt < 4; ++mt)
#pragma unroll
                for (int nt = 0; nt < 4; ++nt)
                    acc[mt][nt] = __builtin_amdgcn_mfma_f32_16x16x32_bf16(
                        af[mt], bfr[nt], acc[mt][nt], 0, 0, 0);
        }
    }

    float bias[4];
#pragma unroll
    for (int nt = 0; nt < 4; ++nt) {
        const int ix = wave * 64 + nt * 16 + arow;
        bias[nt] = fl ? bu32[ix] : bf2f(bu16[ix]);
    }

#pragma unroll
    for (int mt = 0; mt < 4; ++mt) {
#pragma unroll
        for (int reg = 0; reg < 4; ++reg) {
            const int m = mt * 16 + quad * 4 + reg;
            const int node2 = n0 + m;
            if (node2 < NNODES) {
#pragma unroll
                for (int nt = 0; nt < 4; ++nt) {
                    const int n = wave * 64 + nt * 16 + arow;
                    float v = acc[mt][nt][reg] + bias[nt];
                    v = fmaxf(v, 0.f);
                    if (fl) out32[(size_t)node2 * DIM + n] = v;
                    else    out16[(size_t)node2 * DIM + n] = f2bf(v);
                }
            }
        }
    }
}

extern "C" void kernel_launch(void* const* d_in, const int* in_sizes, int n_in,
                              void* d_out, int out_size, void* d_ws, size_t ws_size,
                              hipStream_t stream) {
    // Diagnostic guard: if ws is too small, leave out zeroed (absmax would be 4.40625).
    if (ws_size < (size_t)WS_REQUIRED || d_ws == nullptr) return;

    const unsigned short* nf16 = (const unsigned short*)d_in[0];
    const float*          nf32 = (const float*)d_in[0];
    const unsigned short* ef16 = (const unsigned short*)d_in[1];
    const float*          ef32 = (const float*)d_in[1];
    const int*            ei   = (const int*)d_in[2];
    const unsigned short* Wm16 = (const unsigned short*)d_in[3];
    const float*          Wm32 = (const float*)d_in[3];
    const unsigned short* bm16 = (const unsigned short*)d_in[4];
    const float*          bm32 = (const float*)d_in[4];
    const unsigned short* Wu16 = (const unsigned short*)d_in[5];
    const float*          Wu32 = (const float*)d_in[5];
    const unsigned short* bu16 = (const unsigned short*)d_in[6];
    const float*          bu32 = (const float*)d_in[6];
    unsigned short* out16 = (unsigned short*)d_out;
    float*          out32 = (float*)d_out;

    char* ws = (char*)d_ws;
    float*          agg  = (float*)(ws + AGG_OFF);
    int*            cnt  = (int*)(ws + CNT_OFF);
    unsigned short* Wtm  = (unsigned short*)(ws + WTM_OFF);
    unsigned short* Wtu  = (unsigned short*)(ws + WTU_OFF);
    int*            flag = (int*)(ws + FLAG_OFF);

    // Sort scratch in d_out (fully overwritten by node_k at the end).
    int* perm = (int*)((char*)d_out + PERM_OUT_OFF);
    int* off  = (int*)((char*)d_out + OFF_OUT_OFF);

    hipMemsetAsync(d_ws, 0, ZERO_BYTES, stream);
    detect_k<<<1, 64, 0, stream>>>(nf16, flag);
    transpose_k<<<768, 256, 0, stream>>>(Wm16, Wm32, Wu16, Wu32, Wtm, Wtu, flag);
    count_k<<<(NEDGES + 255) / 256, 256, 0, stream>>>(ei + NEDGES, cnt);
    scan_k<<<1, 1024, 0, stream>>>(cnt, off);
    scatter_k<<<(NEDGES + 255) / 256, 256, 0, stream>>>(ei + NEDGES, off, perm);
    edge_k<<<NEDGES / 64, 256, 0, stream>>>(nf16, nf32, ef16, ef32, ei, ei + NEDGES,
                                            perm, Wtm, bm16, bm32, agg, flag);
    node_k<<<(NNODES + 63) / 64, 256, 0, stream>>>(nf16, nf32, agg, cnt, Wtu,
                                                   bu16, bu32, out16, out32, flag);
}